// Round 1
// baseline (971.471 us; speedup 1.0000x reference)
//
#include <hip/hip_runtime.h>
#include <math.h>

#define BATCH 8
#define CIN 64
#define COUT 64
#define HH 128
#define WW 128
#define KK 9
#define HW (HH*WW)
#define PIX 16

// ---------------- Kernel A: offset conv (3x3, pad 1) -> om[b][pix][32] ----------------
// channels 0..17: raw offsets (dy0,dx0,dy1,dx1,...), 18..26: sigmoid(mask)
__global__ void __launch_bounds__(256) offset_conv_kernel(
        const float* __restrict__ x,
        const float* __restrict__ w_off,
        const float* __restrict__ b_off,
        float* __restrict__ om) {
    int pid = blockIdx.x * blockDim.x + threadIdx.x;  // b*HW + pix
    if (pid >= BATCH * HW) return;
    int b = pid / HW;
    int pix = pid % HW;
    int h = pix / WW;
    int w = pix % WW;

    float acc[27];
#pragma unroll
    for (int i = 0; i < 27; ++i) acc[i] = b_off[i];

    const float* xb = x + (size_t)b * CIN * HW;
    for (int c = 0; c < CIN; ++c) {
        const float* xc = xb + c * HW;
#pragma unroll
        for (int ty = 0; ty < 3; ++ty) {
            int yy = h - 1 + ty;
            bool vy = (yy >= 0) && (yy < HH);
#pragma unroll
            for (int tx = 0; tx < 3; ++tx) {
                int xx = w - 1 + tx;
                bool v = vy && (xx >= 0) && (xx < WW);
                float xv = v ? xc[yy * WW + xx] : 0.0f;
                const float* wp = w_off + c * 9 + ty * 3 + tx;  // stride 576 over ck
#pragma unroll
                for (int ck = 0; ck < 27; ++ck)
                    acc[ck] = fmaf(xv, wp[ck * 576], acc[ck]);
            }
        }
    }

    float* o = om + (size_t)pid * 32;
#pragma unroll
    for (int ck = 0; ck < 18; ++ck) o[ck] = acc[ck];
#pragma unroll
    for (int ck = 18; ck < 27; ++ck) o[ck] = 1.0f / (1.0f + __expf(-acc[ck]));
}

// ---------------- Kernel B: gather + matmul ----------------
__global__ void __launch_bounds__(256) dcn_kernel(
        const float* __restrict__ x,
        const float* __restrict__ om,
        const float* __restrict__ w_dcn,
        float* __restrict__ out) {
    __shared__ float s_val[KK * CIN * PIX];   // [k][c][px]  36.9 KB
    __shared__ float s_geom[KK * PIX * 6];    // [k][px][{y0,x0,w00,w01,w10,w11}]

    int t = threadIdx.x;
    int blk = blockIdx.x;
    int b = blk / (HW / PIX);
    int pix0 = (blk % (HW / PIX)) * PIX;

    // ---- geometry phase ----
    if (t < KK * PIX) {
        int k = t / PIX, px = t % PIX;
        int pix = pix0 + px;
        const float* o = om + (size_t)(b * HW + pix) * 32;
        float dy = o[2 * k], dx = o[2 * k + 1], m = o[18 + k];
        int h = pix / WW, w = pix % WW;
        float py = (float)(h - 1 + k / 3) + dy;
        float pxc = (float)(w - 1 + k % 3) + dx;
        float y0f = floorf(py), x0f = floorf(pxc);
        float wy1 = py - y0f, wx1 = pxc - x0f;
        float wy0 = 1.0f - wy1, wx0 = 1.0f - wx1;
        float* g = s_geom + t * 6;
        g[0] = y0f;
        g[1] = x0f;
        g[2] = wy0 * wx0 * m;
        g[3] = wy0 * wx1 * m;
        g[4] = wy1 * wx0 * m;
        g[5] = wy1 * wx1 * m;
    }
    __syncthreads();

    // ---- gather phase: modulated bilinear samples into LDS ----
    const float* xb = x + (size_t)b * CIN * HW;
    for (int idx = t; idx < KK * CIN * PIX; idx += 256) {
        int k = idx / (CIN * PIX);
        int rem = idx % (CIN * PIX);
        int c = rem / PIX;
        int px = rem % PIX;
        const float* g = s_geom + (k * PIX + px) * 6;
        int y0 = (int)g[0], x0 = (int)g[1];
        const float* xc = xb + c * HW;
        bool y0v = (y0 >= 0) && (y0 < HH);
        bool y1v = (y0 + 1 >= 0) && (y0 + 1 < HH);
        bool x0v = (x0 >= 0) && (x0 < WW);
        bool x1v = (x0 + 1 >= 0) && (x0 + 1 < WW);
        float v00 = (y0v && x0v) ? xc[y0 * WW + x0] : 0.0f;
        float v01 = (y0v && x1v) ? xc[y0 * WW + x0 + 1] : 0.0f;
        float v10 = (y1v && x0v) ? xc[(y0 + 1) * WW + x0] : 0.0f;
        float v11 = (y1v && x1v) ? xc[(y0 + 1) * WW + x0 + 1] : 0.0f;
        s_val[idx] = g[2] * v00 + g[3] * v01 + g[4] * v10 + g[5] * v11;
    }
    __syncthreads();

    // ---- matmul phase: out[o] = sum_{c,k} val[c,k] * w[o,c,k] ----
    int px = t % PIX;
    int og = t / PIX;  // 0..15, each handles 4 consecutive o
    float acc[4] = {0.f, 0.f, 0.f, 0.f};
    for (int c = 0; c < CIN; ++c) {
#pragma unroll
        for (int k = 0; k < KK; ++k) {
            float v = s_val[(k * CIN + c) * PIX + px];
#pragma unroll
            for (int j = 0; j < 4; ++j) {
                acc[j] = fmaf(v, w_dcn[(size_t)(og * 4 + j) * (CIN * KK) + c * KK + k], acc[j]);
            }
        }
    }
    float* ob = out + (size_t)b * COUT * HW + pix0 + px;
#pragma unroll
    for (int j = 0; j < 4; ++j)
        ob[(size_t)(og * 4 + j) * HW] = acc[j];
}

extern "C" void kernel_launch(void* const* d_in, const int* in_sizes, int n_in,
                              void* d_out, int out_size, void* d_ws, size_t ws_size,
                              hipStream_t stream) {
    (void)in_sizes; (void)n_in; (void)out_size; (void)ws_size;
    const float* x        = (const float*)d_in[0];
    const float* w_offset = (const float*)d_in[1];
    const float* b_offset = (const float*)d_in[2];
    const float* w_dcn    = (const float*)d_in[3];
    float* out = (float*)d_out;
    float* om  = (float*)d_ws;  // BATCH*HW*32 floats = 16.8 MB

    offset_conv_kernel<<<(BATCH * HW + 255) / 256, 256, 0, stream>>>(x, w_offset, b_offset, om);
    dcn_kernel<<<BATCH * (HW / PIX), 256, 0, stream>>>(x, om, w_dcn, out);
}

// Round 2
// 485.739 us; speedup vs baseline: 2.0000x; 2.0000x over previous
//
#include <hip/hip_runtime.h>
#include <math.h>

#define BATCH 8
#define CIN 64
#define COUT 64
#define HH 128
#define WW 128
#define KF 9
#define HW (HH*WW)
#define PIX 32
#define KDIM 576   // K index = kf*64 + c

typedef __attribute__((ext_vector_type(8))) short short8;
typedef __attribute__((ext_vector_type(4))) float f32x4;

__device__ __forceinline__ unsigned short f2bf(float f) {
    union { float f; unsigned int u; } v; v.f = f;
    unsigned int u = v.u;
    u += 0x7FFFu + ((u >> 16) & 1u);   // RNE
    return (unsigned short)(u >> 16);
}

// ---------------- Kernel A: offset conv (3x3, pad 1) -> om[b][pix][32] ----------------
__global__ void __launch_bounds__(256) offset_conv_kernel(
        const float* __restrict__ x,
        const float* __restrict__ w_off,
        const float* __restrict__ b_off,
        float* __restrict__ om) {
    int pid = blockIdx.x * blockDim.x + threadIdx.x;
    if (pid >= BATCH * HW) return;
    int b = pid / HW;
    int pix = pid % HW;
    int h = pix / WW;
    int w = pix % WW;

    float acc[27];
#pragma unroll
    for (int i = 0; i < 27; ++i) acc[i] = b_off[i];

    const float* xb = x + (size_t)b * CIN * HW;
    for (int c = 0; c < CIN; ++c) {
        const float* xc = xb + c * HW;
#pragma unroll
        for (int ty = 0; ty < 3; ++ty) {
            int yy = h - 1 + ty;
            bool vy = (yy >= 0) && (yy < HH);
#pragma unroll
            for (int tx = 0; tx < 3; ++tx) {
                int xx = w - 1 + tx;
                bool v = vy && (xx >= 0) && (xx < WW);
                float xv = v ? xc[yy * WW + xx] : 0.0f;
                const float* wp = w_off + c * 9 + ty * 3 + tx;
#pragma unroll
                for (int ck = 0; ck < 27; ++ck)
                    acc[ck] = fmaf(xv, wp[ck * 576], acc[ck]);
            }
        }
    }

    float* o = om + (size_t)pid * 32;
#pragma unroll
    for (int ck = 0; ck < 18; ++ck) o[ck] = acc[ck];
#pragma unroll
    for (int ck = 18; ck < 27; ++ck) o[ck] = 1.0f / (1.0f + __expf(-acc[ck]));
}

// ---------------- Kernel W: w_dcn[o][c][kf] fp32 -> w_t[o][kf*64+c] bf16 ----------------
__global__ void wcast_kernel(const float* __restrict__ w, unsigned short* __restrict__ wt) {
    int i = blockIdx.x * 256 + threadIdx.x;
    if (i >= COUT * KDIM) return;
    int o = i / KDIM, k = i % KDIM;
    int kf = k >> 6, c = k & 63;
    wt[i] = f2bf(w[(o * 64 + c) * 9 + kf]);
}

// ---------------- Kernel B: gather (fp32) -> LDS bf16 -> MFMA ----------------
__global__ void __launch_bounds__(256) dcn_mfma_kernel(
        const float* __restrict__ x,
        const float* __restrict__ om,
        const unsigned short* __restrict__ wt,
        float* __restrict__ out) {
    __shared__ char  s_val[PIX * KDIM * 2];     // swizzled [px][k] bf16, 36864 B
    __shared__ float s_geom[PIX * KF * 6];      // 6912 B

    int t = threadIdx.x;
    int blk = blockIdx.x;
    int b = blk / (HW / PIX);
    int pix0 = (blk % (HW / PIX)) * PIX;

    // ---- geometry: 288 items ----
    for (int idx = t; idx < PIX * KF; idx += 256) {
        int px = idx / KF, kf = idx % KF;
        int pix = pix0 + px;
        const float* o = om + (size_t)(b * HW + pix) * 32;
        float dy = o[2 * kf], dx = o[2 * kf + 1], m = o[18 + kf];
        int h = pix / WW, w = pix % WW;
        float py  = (float)(h - 1 + kf / 3) + dy;
        float pxf = (float)(w - 1 + kf % 3) + dx;
        float y0f = floorf(py), x0f = floorf(pxf);
        float wy1 = py - y0f, wx1 = pxf - x0f;
        float wy0 = 1.f - wy1, wx0 = 1.f - wx1;
        float* g = s_geom + idx * 6;
        g[0] = y0f; g[1] = x0f;
        g[2] = wy0 * wx0 * m; g[3] = wy0 * wx1 * m;
        g[4] = wy1 * wx0 * m; g[5] = wy1 * wx1 * m;
    }
    __syncthreads();

    // ---- gather: 9216 bf16-pair items, idx = (kf*32+cp)*32 + px ----
    const float* xb = x + (size_t)b * CIN * HW;
#pragma unroll 2
    for (int it = 0; it < 36; ++it) {
        int idx = it * 256 + t;
        int px = idx & 31;
        int rem = idx >> 5;
        int cp = rem & 31;
        int kf = rem >> 5;
        const float* g = s_geom + (px * KF + kf) * 6;
        int y0 = (int)g[0], x0 = (int)g[1];
        bool y0v = (unsigned)y0 < (unsigned)HH;
        bool y1v = (unsigned)(y0 + 1) < (unsigned)HH;
        bool x0v = (unsigned)x0 < (unsigned)WW;
        bool x1v = (unsigned)(x0 + 1) < (unsigned)WW;
        const float* xc0 = xb + (size_t)(cp * 2) * HW;
        const float* xc1 = xc0 + HW;
        int i00 = y0 * WW + x0;
        float v00a = 0.f, v01a = 0.f, v10a = 0.f, v11a = 0.f;
        float v00b = 0.f, v01b = 0.f, v10b = 0.f, v11b = 0.f;
        if (y0v & x0v) { v00a = xc0[i00];          v00b = xc1[i00]; }
        if (y0v & x1v) { v01a = xc0[i00 + 1];      v01b = xc1[i00 + 1]; }
        if (y1v & x0v) { v10a = xc0[i00 + WW];     v10b = xc1[i00 + WW]; }
        if (y1v & x1v) { v11a = xc0[i00 + WW + 1]; v11b = xc1[i00 + WW + 1]; }
        float va = g[2] * v00a + g[3] * v01a + g[4] * v10a + g[5] * v11a;
        float vb = g[2] * v00b + g[3] * v01b + g[4] * v10b + g[5] * v11b;
        unsigned int dw = (unsigned int)f2bf(va) | ((unsigned int)f2bf(vb) << 16);
        int baddr = (px * KDIM + (kf * 64 + cp * 2)) * 2;
        baddr ^= (px & 7) << 4;
        *(unsigned int*)(s_val + baddr) = dw;
    }
    __syncthreads();

    // ---- MFMA: each wave 16px x 32out, A=w (M=out), B=val (N=px) ----
    int lane = t & 63;
    int wv = t >> 6;
    int px_base = (wv & 1) * 16;
    int out_base = (wv >> 1) * 32;
    int l15 = lane & 15;
    int g4 = lane >> 4;

    f32x4 acc0 = {0.f, 0.f, 0.f, 0.f};
    f32x4 acc1 = {0.f, 0.f, 0.f, 0.f};
    const unsigned short* wrow0 = wt + (size_t)(out_base + l15) * KDIM;
    const unsigned short* wrow1 = wrow0 + 16 * KDIM;
    int vrow = px_base + l15;
    int vbase = vrow * KDIM * 2;
    int vswz = (vrow & 7) << 4;
#pragma unroll
    for (int kk = 0; kk < 18; ++kk) {
        int k0 = kk * 32 + g4 * 8;
        short8 bfrag = *(const short8*)(s_val + ((vbase + k0 * 2) ^ vswz));
        short8 a0 = *(const short8*)(wrow0 + k0);
        short8 a1 = *(const short8*)(wrow1 + k0);
        acc0 = __builtin_amdgcn_mfma_f32_16x16x32_bf16(a0, bfrag, acc0, 0, 0, 0);
        acc1 = __builtin_amdgcn_mfma_f32_16x16x32_bf16(a1, bfrag, acc1, 0, 0, 0);
    }

    // ---- store: D[m=out][n=px]: px = lane&15, out = g4*4 + r (+tile*16) ----
    float* ob = out + (size_t)b * COUT * HW + pix0 + px_base + l15;
    int orow0 = out_base + g4 * 4;
#pragma unroll
    for (int r = 0; r < 4; ++r) {
        ob[(size_t)(orow0 + r) * HW]      = acc0[r];
        ob[(size_t)(orow0 + 16 + r) * HW] = acc1[r];
    }
}

extern "C" void kernel_launch(void* const* d_in, const int* in_sizes, int n_in,
                              void* d_out, int out_size, void* d_ws, size_t ws_size,
                              hipStream_t stream) {
    (void)in_sizes; (void)n_in; (void)out_size; (void)ws_size;
    const float* x        = (const float*)d_in[0];
    const float* w_offset = (const float*)d_in[1];
    const float* b_offset = (const float*)d_in[2];
    const float* w_dcn    = (const float*)d_in[3];
    float* out = (float*)d_out;
    float* om  = (float*)d_ws;                               // 16,777,216 B
    unsigned short* wt = (unsigned short*)((char*)d_ws + (size_t)BATCH * HW * 32 * 4);

    offset_conv_kernel<<<(BATCH * HW + 255) / 256, 256, 0, stream>>>(x, w_offset, b_offset, om);
    wcast_kernel<<<(COUT * KDIM + 255) / 256, 256, 0, stream>>>(w_dcn, wt);
    dcn_mfma_kernel<<<BATCH * (HW / PIX), 256, 0, stream>>>(x, om, wt, out);
}

// Round 4
// 176.147 us; speedup vs baseline: 5.5151x; 2.7576x over previous
//
#include <hip/hip_runtime.h>
#include <math.h>

#define BATCH 8
#define CIN 64
#define COUT 64
#define HH 128
#define WW 128
#define KF9 9
#define HW (HH*WW)
#define PIX 32
#define KDIM 576   // K index = kf*64 + c

typedef __attribute__((ext_vector_type(8))) short short8;
typedef __attribute__((ext_vector_type(4))) float f32x4;

__device__ __forceinline__ unsigned short f2bf(float f) {
    union { float f; unsigned int u; } v; v.f = f;
    unsigned int u = v.u;
    u += 0x7FFFu + ((u >> 16) & 1u);   // RNE
    return (unsigned short)(u >> 16);
}
__device__ __forceinline__ float bf2f_s(short s) {
    union { unsigned int u; float f; } v;
    v.u = ((unsigned int)(unsigned short)s) << 16;
    return v.f;
}

// ---------------- Kernel 1: x[b][c][h][w] fp32 -> xT[b][h][w][c] bf16 ----------------
__global__ void __launch_bounds__(256) xpose_kernel(const float* __restrict__ x,
                                                    unsigned short* __restrict__ xT) {
    int idx = blockIdx.x * 256 + threadIdx.x;   // 1,048,576 total
    int c8 = idx & 7;
    int w  = (idx >> 3) & 127;
    int h  = (idx >> 10) & 127;
    int b  = idx >> 17;
    const float* xp = x + (((size_t)(b * 64 + c8 * 8) * 128 + h) * 128 + w);
    short8 o;
#pragma unroll
    for (int j = 0; j < 8; ++j)
        o[j] = (short)f2bf(xp[(size_t)j * HW]);
    *(short8*)(xT + (size_t)idx * 8) = o;
}

// ---------------- Kernel 2: weight casts/reorders to [o][kf*64+c] bf16 ----------------
__global__ void __launch_bounds__(256) wcast_kernel(const float* __restrict__ w_dcn,
                                                    const float* __restrict__ w_off,
                                                    unsigned short* __restrict__ wt,
                                                    unsigned short* __restrict__ wtoff) {
    int i = blockIdx.x * 256 + threadIdx.x;
    if (i < COUT * KDIM) {
        int o = i / KDIM, k = i % KDIM;
        int kf = k >> 6, c = k & 63;
        wt[i] = f2bf(w_dcn[(o * 64 + c) * 9 + kf]);
    } else {
        int i2 = i - COUT * KDIM;
        if (i2 < 32 * KDIM) {
            int o = i2 / KDIM, k = i2 % KDIM;
            int kf = k >> 6, c = k & 63;
            wtoff[i2] = (o < 27) ? f2bf(w_off[(o * 64 + c) * 9 + kf]) : (unsigned short)0;
        }
    }
}

// ---------------- Kernel 3: fused conv-MFMA + geometry + gather + main MFMA ----------------
__global__ void __launch_bounds__(256) fused_dcn_kernel(
        const unsigned short* __restrict__ xT,
        const unsigned short* __restrict__ wtoff,
        const float* __restrict__ b_off,
        const unsigned short* __restrict__ wt,
        float* __restrict__ out) {
    __shared__ float s_om[PIX * 33];            // conv result, padded stride 33
    __shared__ float s_geom[PIX * KF9 * 6];
    __shared__ char  s_val[PIX * KDIM * 2];     // swizzled [px][k] bf16

    int t = threadIdx.x;
    int blk0 = blockIdx.x;
    int blk = (blk0 & 7) * 512 + (blk0 >> 3);   // XCD swizzle (4096 = 8*512, bijective)
    int b = blk >> 9;
    int rem = blk & 511;
    int h = rem >> 2;                            // tile = 32 px of one row
    int w0 = (rem & 3) << 5;

    int lane = t & 63;
    int wv = t >> 6;
    int l15 = lane & 15;
    int g4 = lane >> 4;

    const unsigned short* xTb = xT + (size_t)b * HW * 64;

    // ---- phase A: offset conv (27ch, pad to 32) via MFMA, im2col direct from xT ----
    {
        int Nt = wv & 1, Mt = wv >> 1;
        int px = Nt * 16 + l15;
        int colbase = w0 + px - 1;
        f32x4 acc = {0.f, 0.f, 0.f, 0.f};
        const unsigned short* arow = wtoff + (size_t)(Mt * 16 + l15) * KDIM;
#pragma unroll
        for (int kk = 0; kk < 18; ++kk) {
            int kf = kk >> 1;
            int ky = kf / 3, kx = kf % 3;
            int cb = (kk & 1) * 32 + g4 * 8;
            int row = h - 1 + ky;
            int col = colbase + kx;
            short8 bfrag = {0, 0, 0, 0, 0, 0, 0, 0};
            if ((unsigned)row < 128u && (unsigned)col < 128u)
                bfrag = *(const short8*)(xTb + ((size_t)row * 128 + (size_t)col) * 64 + cb);
            short8 afrag = *(const short8*)(arow + kk * 32 + g4 * 8);
            acc = __builtin_amdgcn_mfma_f32_16x16x32_bf16(afrag, bfrag, acc, 0, 0, 0);
        }
        int ob = Mt * 16 + g4 * 4;
#pragma unroll
        for (int r = 0; r < 4; ++r) {
            float bias = (ob + r < 27) ? b_off[ob + r] : 0.f;
            s_om[px * 33 + ob + r] = acc[r] + bias;
        }
    }
    __syncthreads();

    // ---- phase B: geometry (288 items, strided over 256 threads) ----
    for (int idx = t; idx < PIX * KF9; idx += 256) {
        int px = idx / 9, kf = idx % 9;
        const float* o = s_om + px * 33;
        float dy = o[2 * kf], dx = o[2 * kf + 1];
        float m = 1.0f / (1.0f + __expf(-o[18 + kf]));
        int w = w0 + px;
        float py  = (float)(h - 1 + kf / 3) + dy;
        float pxf = (float)(w - 1 + kf % 3) + dx;
        float y0f = floorf(py), x0f = floorf(pxf);
        float wy1 = py - y0f, wx1 = pxf - x0f;
        float wy0 = 1.f - wy1, wx0 = 1.f - wx1;
        float* g = s_geom + idx * 6;
        g[0] = y0f; g[1] = x0f;
        g[2] = wy0 * wx0 * m; g[3] = wy0 * wx1 * m;
        g[4] = wy1 * wx0 * m; g[5] = wy1 * wx1 * m;
    }
    __syncthreads();

    // ---- phase C: gather, vectorized over channels (thread = (px, c-chunk)) ----
    {
        int px = t >> 3, cl = t & 7;
        int sbase = px * KDIM;
#pragma unroll
        for (int kf = 0; kf < 9; ++kf) {
            const float* g = s_geom + (px * 9 + kf) * 6;
            int y0 = (int)g[0], x0 = (int)g[1];
            float w00 = g[2], w01 = g[3], w10 = g[4], w11 = g[5];
            bool y0v = (unsigned)y0 < 128u;
            bool y1v = (unsigned)(y0 + 1) < 128u;
            bool x0v = (unsigned)x0 < 128u;
            bool x1v = (unsigned)(x0 + 1) < 128u;
            const unsigned short* base = xTb + ((long)y0 * 128 + (long)x0) * 64 + cl * 8;
            short8 v00 = {0,0,0,0,0,0,0,0}, v01 = {0,0,0,0,0,0,0,0};
            short8 v10 = {0,0,0,0,0,0,0,0}, v11 = {0,0,0,0,0,0,0,0};
            if (y0v && x0v) v00 = *(const short8*)(base);
            if (y0v && x1v) v01 = *(const short8*)(base + 64);
            if (y1v && x0v) v10 = *(const short8*)(base + 8192);
            if (y1v && x1v) v11 = *(const short8*)(base + 8192 + 64);
            short8 res;
#pragma unroll
            for (int j = 0; j < 8; ++j) {
                float f = w00 * bf2f_s(v00[j]) + w01 * bf2f_s(v01[j])
                        + w10 * bf2f_s(v10[j]) + w11 * bf2f_s(v11[j]);
                res[j] = (short)f2bf(f);
            }
            int baddr = ((sbase + kf * 64 + cl * 8) * 2) ^ ((px & 7) << 4);
            *(short8*)(s_val + baddr) = res;
        }
    }
    __syncthreads();

    // ---- phase D: main MFMA, each wave 16px x 32out ----
    {
        int px_base = (wv & 1) * 16;
        int out_base = (wv >> 1) * 32;
        f32x4 acc0 = {0.f, 0.f, 0.f, 0.f};
        f32x4 acc1 = {0.f, 0.f, 0.f, 0.f};
        const unsigned short* wrow0 = wt + (size_t)(out_base + l15) * KDIM;
        const unsigned short* wrow1 = wrow0 + 16 * KDIM;
        int vrow = px_base + l15;
        int vbase = vrow * KDIM * 2;
        int vswz = (vrow & 7) << 4;
#pragma unroll
        for (int kk = 0; kk < 18; ++kk) {
            int k0 = kk * 32 + g4 * 8;
            short8 bfrag = *(const short8*)(s_val + ((vbase + k0 * 2) ^ vswz));
            short8 a0 = *(const short8*)(wrow0 + k0);
            short8 a1 = *(const short8*)(wrow1 + k0);
            acc0 = __builtin_amdgcn_mfma_f32_16x16x32_bf16(a0, bfrag, acc0, 0, 0, 0);
            acc1 = __builtin_amdgcn_mfma_f32_16x16x32_bf16(a1, bfrag, acc1, 0, 0, 0);
        }
        float* obp = out + (size_t)b * COUT * HW + (size_t)h * WW + w0 + px_base + l15;
        int orow0 = out_base + g4 * 4;
#pragma unroll
        for (int r = 0; r < 4; ++r) {
            obp[(size_t)(orow0 + r) * HW]      = acc0[r];
            obp[(size_t)(orow0 + 16 + r) * HW] = acc1[r];
        }
    }
}

extern "C" void kernel_launch(void* const* d_in, const int* in_sizes, int n_in,
                              void* d_out, int out_size, void* d_ws, size_t ws_size,
                              hipStream_t stream) {
    (void)in_sizes; (void)n_in; (void)out_size; (void)ws_size;
    const float* x        = (const float*)d_in[0];
    const float* w_offset = (const float*)d_in[1];
    const float* b_offset = (const float*)d_in[2];
    const float* w_dcn    = (const float*)d_in[3];
    float* out = (float*)d_out;

    unsigned short* xT    = (unsigned short*)d_ws;                      // 16,777,216 B
    unsigned short* wt    = (unsigned short*)((char*)d_ws + 16777216);  // 73,728 B
    unsigned short* wtoff = (unsigned short*)((char*)d_ws + 16850944);  // 36,864 B

    xpose_kernel<<<4096, 256, 0, stream>>>(x, xT);
    wcast_kernel<<<216, 256, 0, stream>>>(w_dcn, w_offset, wt, wtoff);
    fused_dcn_kernel<<<4096, 256, 0, stream>>>(xT, wtoff, b_offset, wt, out);
}

// Round 5
// 173.557 us; speedup vs baseline: 5.5974x; 1.0149x over previous
//
#include <hip/hip_runtime.h>
#include <math.h>

#define BATCH 8
#define CIN 64
#define COUT 64
#define HH 128
#define WW 128
#define HW (HH*WW)
#define PIX 32
#define KDIM 576   // K index = kf*64 + c
#define KLOC 320   // max K columns resident in LDS (kf-half of 5)

typedef __attribute__((ext_vector_type(8))) short short8;
typedef __attribute__((ext_vector_type(4))) float f32x4;

__device__ __forceinline__ unsigned short f2bf(float f) {
    union { float f; unsigned int u; } v; v.f = f;
    unsigned int u = v.u;
    u += 0x7FFFu + ((u >> 16) & 1u);   // RNE
    return (unsigned short)(u >> 16);
}
__device__ __forceinline__ float bf2f_s(short s) {
    union { unsigned int u; float f; } v;
    v.u = ((unsigned int)(unsigned short)s) << 16;
    return v.f;
}

// ---------------- Kernel 1: x[b][c][h][w] fp32 -> xT[b][h][w][c] bf16 ----------------
__global__ void __launch_bounds__(256) xpose_kernel(const float* __restrict__ x,
                                                    unsigned short* __restrict__ xT) {
    int idx = blockIdx.x * 256 + threadIdx.x;   // 1,048,576 total
    int c8 = idx & 7;
    int w  = (idx >> 3) & 127;
    int h  = (idx >> 10) & 127;
    int b  = idx >> 17;
    const float* xp = x + (((size_t)(b * 64 + c8 * 8) * 128 + h) * 128 + w);
    short8 o;
#pragma unroll
    for (int j = 0; j < 8; ++j)
        o[j] = (short)f2bf(xp[(size_t)j * HW]);
    *(short8*)(xT + (size_t)idx * 8) = o;
}

// ---------------- Kernel 2: weight casts/reorders to [o][kf*64+c] bf16 ----------------
__global__ void __launch_bounds__(256) wcast_kernel(const float* __restrict__ w_dcn,
                                                    const float* __restrict__ w_off,
                                                    unsigned short* __restrict__ wt,
                                                    unsigned short* __restrict__ wtoff) {
    int i = blockIdx.x * 256 + threadIdx.x;
    if (i < COUT * KDIM) {
        int o = i / KDIM, k = i % KDIM;
        int kf = k >> 6, c = k & 63;
        wt[i] = f2bf(w_dcn[(o * 64 + c) * 9 + kf]);
    } else {
        int i2 = i - COUT * KDIM;
        if (i2 < 32 * KDIM) {
            int o = i2 / KDIM, k = i2 % KDIM;
            int kf = k >> 6, c = k & 63;
            wtoff[i2] = (o < 27) ? f2bf(w_off[(o * 64 + c) * 9 + kf]) : (unsigned short)0;
        }
    }
}

// ---------------- fused kernel helpers ----------------
template<int KF0, int KF1>
__device__ __forceinline__ void gather_half(
        const unsigned short* __restrict__ xTb,
        const float* __restrict__ s_om,
        char* __restrict__ s_val,
        int t, int h, int w0) {
    int px = t >> 3, cl = t & 7;
    const float* o = s_om + px * 28;
    int w = w0 + px;
#pragma unroll
    for (int kf = KF0; kf < KF1; ++kf) {
        float dy = o[2 * kf], dx = o[2 * kf + 1];
        float m = 1.0f / (1.0f + __expf(-o[18 + kf]));
        float py  = (float)(h - 1 + kf / 3) + dy;
        float pxf = (float)(w - 1 + kf % 3) + dx;
        float y0f = floorf(py), x0f = floorf(pxf);
        float wy1 = py - y0f, wx1 = pxf - x0f;
        float wy0 = 1.f - wy1, wx0 = 1.f - wx1;
        float w00 = wy0 * wx0 * m, w01 = wy0 * wx1 * m;
        float w10 = wy1 * wx0 * m, w11 = wy1 * wx1 * m;
        int y0 = (int)y0f, x0 = (int)x0f;
        bool y0v = (unsigned)y0 < 128u;
        bool y1v = (unsigned)(y0 + 1) < 128u;
        bool x0v = (unsigned)x0 < 128u;
        bool x1v = (unsigned)(x0 + 1) < 128u;
        const unsigned short* base = xTb + ((long)y0 * 128 + (long)x0) * 64 + cl * 8;
        short8 v00 = {0,0,0,0,0,0,0,0}, v01 = {0,0,0,0,0,0,0,0};
        short8 v10 = {0,0,0,0,0,0,0,0}, v11 = {0,0,0,0,0,0,0,0};
        if (y0v && x0v) v00 = *(const short8*)(base);
        if (y0v && x1v) v01 = *(const short8*)(base + 64);
        if (y1v && x0v) v10 = *(const short8*)(base + 8192);
        if (y1v && x1v) v11 = *(const short8*)(base + 8192 + 64);
        short8 res;
#pragma unroll
        for (int j = 0; j < 8; ++j) {
            float f = w00 * bf2f_s(v00[j]) + w01 * bf2f_s(v01[j])
                    + w10 * bf2f_s(v10[j]) + w11 * bf2f_s(v11[j]);
            res[j] = (short)f2bf(f);
        }
        int baddr = ((px * KLOC + (kf - KF0) * 64 + cl * 8) * 2) ^ ((px & 7) << 4);
        *(short8*)(s_val + baddr) = res;
    }
}

template<int NK>
__device__ __forceinline__ void mfma_half(
        const unsigned short* __restrict__ wrow0,
        const unsigned short* __restrict__ wrow1,
        const char* __restrict__ s_val,
        int vbase, int vswz, int g4,
        f32x4& acc0, f32x4& acc1) {
#pragma unroll
    for (int kk = 0; kk < NK; ++kk) {
        int k0 = kk * 32 + g4 * 8;
        short8 bfrag = *(const short8*)(s_val + ((vbase + k0 * 2) ^ vswz));
        short8 a0 = *(const short8*)(wrow0 + k0);
        short8 a1 = *(const short8*)(wrow1 + k0);
        acc0 = __builtin_amdgcn_mfma_f32_16x16x32_bf16(a0, bfrag, acc0, 0, 0, 0);
        acc1 = __builtin_amdgcn_mfma_f32_16x16x32_bf16(a1, bfrag, acc1, 0, 0, 0);
    }
}

// ---------------- Kernel 3: fused conv-MFMA + gather + split-K MFMA ----------------
__global__ void __launch_bounds__(256, 6) fused_dcn_kernel(
        const unsigned short* __restrict__ xT,
        const unsigned short* __restrict__ wtoff,
        const float* __restrict__ b_off,
        const unsigned short* __restrict__ wt,
        float* __restrict__ out) {
    __shared__ float s_om[PIX * 28];            // 3584 B (stride 28, 27 used)
    __shared__ char  s_val[PIX * KLOC * 2];     // 20480 B, swizzled [px][k'] bf16

    int t = threadIdx.x;
    int blk0 = blockIdx.x;
    int blk = (blk0 & 7) * 512 + (blk0 >> 3);   // XCD swizzle (4096 = 8*512, bijective)
    int b = blk >> 9;
    int rem = blk & 511;
    int h = rem >> 2;                            // tile = 32 px of one row
    int w0 = (rem & 3) << 5;

    int lane = t & 63;
    int wv = t >> 6;
    int l15 = lane & 15;
    int g4 = lane >> 4;

    const unsigned short* xTb = xT + (size_t)b * HW * 64;

    // ---- phase A: offset conv (27ch) via MFMA, im2col direct from xT ----
    {
        int Nt = wv & 1, Mt = wv >> 1;
        int px = Nt * 16 + l15;
        int colbase = w0 + px - 1;
        f32x4 acc = {0.f, 0.f, 0.f, 0.f};
        const unsigned short* arow = wtoff + (size_t)(Mt * 16 + l15) * KDIM;
#pragma unroll
        for (int kk = 0; kk < 18; ++kk) {
            int kf = kk >> 1;
            int ky = kf / 3, kx = kf % 3;
            int cb = (kk & 1) * 32 + g4 * 8;
            int row = h - 1 + ky;
            int col = colbase + kx;
            short8 bfrag = {0, 0, 0, 0, 0, 0, 0, 0};
            if ((unsigned)row < 128u && (unsigned)col < 128u)
                bfrag = *(const short8*)(xTb + ((size_t)row * 128 + (size_t)col) * 64 + cb);
            short8 afrag = *(const short8*)(arow + kk * 32 + g4 * 8);
            acc = __builtin_amdgcn_mfma_f32_16x16x32_bf16(afrag, bfrag, acc, 0, 0, 0);
        }
        int ob = Mt * 16 + g4 * 4;
#pragma unroll
        for (int r = 0; r < 4; ++r) {
            if (ob + r < 27)
                s_om[px * 28 + ob + r] = acc[r] + b_off[ob + r];
        }
    }
    __syncthreads();

    // ---- main GEMM state (per wave: 16px x 32out) ----
    int px_base = (wv & 1) * 16;
    int out_base = (wv >> 1) * 32;
    f32x4 acc0 = {0.f, 0.f, 0.f, 0.f};
    f32x4 acc1 = {0.f, 0.f, 0.f, 0.f};
    const unsigned short* wrow0 = wt + (size_t)(out_base + l15) * KDIM;
    const unsigned short* wrow1 = wrow0 + 16 * KDIM;
    int vrow = px_base + l15;
    int vbase = vrow * KLOC * 2;
    int vswz = (vrow & 7) << 4;

    // ---- half 0: kf 0..3 (K' = 256) ----
    gather_half<0, 4>(xTb, s_om, s_val, t, h, w0);
    __syncthreads();
    mfma_half<8>(wrow0, wrow1, s_val, vbase, vswz, g4, acc0, acc1);
    __syncthreads();

    // ---- half 1: kf 4..8 (K' = 320) ----
    gather_half<4, 9>(xTb, s_om, s_val, t, h, w0);
    __syncthreads();
    mfma_half<10>(wrow0 + 256, wrow1 + 256, s_val, vbase, vswz, g4, acc0, acc1);

    // ---- store ----
    float* obp = out + (size_t)b * COUT * HW + (size_t)h * WW + w0 + px_base + l15;
    int orow0 = out_base + g4 * 4;
#pragma unroll
    for (int r = 0; r < 4; ++r) {
        obp[(size_t)(orow0 + r) * HW]      = acc0[r];
        obp[(size_t)(orow0 + 16 + r) * HW] = acc1[r];
    }
}

extern "C" void kernel_launch(void* const* d_in, const int* in_sizes, int n_in,
                              void* d_out, int out_size, void* d_ws, size_t ws_size,
                              hipStream_t stream) {
    (void)in_sizes; (void)n_in; (void)out_size; (void)ws_size;
    const float* x        = (const float*)d_in[0];
    const float* w_offset = (const float*)d_in[1];
    const float* b_offset = (const float*)d_in[2];
    const float* w_dcn    = (const float*)d_in[3];
    float* out = (float*)d_out;

    unsigned short* xT    = (unsigned short*)d_ws;                      // 16,777,216 B
    unsigned short* wt    = (unsigned short*)((char*)d_ws + 16777216);  // 73,728 B
    unsigned short* wtoff = (unsigned short*)((char*)d_ws + 16850944);  // 36,864 B

    xpose_kernel<<<4096, 256, 0, stream>>>(x, xT);
    wcast_kernel<<<216, 256, 0, stream>>>(w_dcn, w_offset, wt, wtoff);
    fused_dcn_kernel<<<4096, 256, 0, stream>>>(xT, wtoff, b_offset, wt, out);
}

// Round 6
// 166.992 us; speedup vs baseline: 5.8175x; 1.0393x over previous
//
#include <hip/hip_runtime.h>
#include <math.h>

#define BATCH 8
#define CIN 64
#define COUT 64
#define HH 128
#define WW 128
#define HW (HH*WW)
#define PIX 32
#define KDIM 576   // K index = kf*64 + c
#define KLOC 320   // max K columns resident in LDS (kf-half of 5)

typedef __attribute__((ext_vector_type(8))) short short8;
typedef __attribute__((ext_vector_type(4))) float f32x4;

__device__ __forceinline__ unsigned short f2bf(float f) {
    union { float f; unsigned int u; } v; v.f = f;
    unsigned int u = v.u;
    u += 0x7FFFu + ((u >> 16) & 1u);   // RNE
    return (unsigned short)(u >> 16);
}
__device__ __forceinline__ float bf2f_s(short s) {
    union { unsigned int u; float f; } v;
    v.u = ((unsigned int)(unsigned short)s) << 16;
    return v.f;
}

// ---------------- Kernel 1: x[b][c][h][w] fp32 -> xT[b][h][w][c] bf16 ----------------
__global__ void __launch_bounds__(256) xpose_kernel(const float* __restrict__ x,
                                                    unsigned short* __restrict__ xT) {
    int idx = blockIdx.x * 256 + threadIdx.x;   // 1,048,576 total
    int c8 = idx & 7;
    int w  = (idx >> 3) & 127;
    int h  = (idx >> 10) & 127;
    int b  = idx >> 17;
    const float* xp = x + (((size_t)(b * 64 + c8 * 8) * 128 + h) * 128 + w);
    short8 o;
#pragma unroll
    for (int j = 0; j < 8; ++j)
        o[j] = (short)f2bf(xp[(size_t)j * HW]);
    *(short8*)(xT + (size_t)idx * 8) = o;
}

// ---------------- Kernel 2: weight casts/reorders to [o][kf*64+c] bf16 ----------------
__global__ void __launch_bounds__(256) wcast_kernel(const float* __restrict__ w_dcn,
                                                    const float* __restrict__ w_off,
                                                    unsigned short* __restrict__ wt,
                                                    unsigned short* __restrict__ wtoff) {
    int i = blockIdx.x * 256 + threadIdx.x;
    if (i < COUT * KDIM) {
        int o = i / KDIM, k = i % KDIM;
        int kf = k >> 6, c = k & 63;
        wt[i] = f2bf(w_dcn[(o * 64 + c) * 9 + kf]);
    } else {
        int i2 = i - COUT * KDIM;
        if (i2 < 32 * KDIM) {
            int o = i2 / KDIM, k = i2 % KDIM;
            int kf = k >> 6, c = k & 63;
            wtoff[i2] = (o < 27) ? f2bf(w_off[(o * 64 + c) * 9 + kf]) : (unsigned short)0;
        }
    }
}

// ---------------- fused kernel helpers ----------------
// Branch-free gather: clamp corner indices, fold validity into weights
// (identical semantics to the reference's clip + valid-mask).
template<int KF0, int KF1>
__device__ __forceinline__ void gather_half(
        const unsigned short* __restrict__ xTb,
        const float* __restrict__ s_om,
        char* __restrict__ s_val,
        int t, int h, int w0) {
    constexpr int NKF = KF1 - KF0;
    int px = t >> 3, cl = t & 7;
    const float* o = s_om + px * 28;
    int w = w0 + px;

    float w00[NKF], w01[NKF], w10[NKF], w11[NKF];
    int o00[NKF], o01[NKF], o10[NKF], o11[NKF];
#pragma unroll
    for (int kf = KF0; kf < KF1; ++kf) {
        const int i = kf - KF0;
        float dy = o[2 * kf], dx = o[2 * kf + 1];
        float m = 1.0f / (1.0f + __expf(-o[18 + kf]));
        float py  = (float)(h - 1 + kf / 3) + dy;
        float pxf = (float)(w - 1 + kf % 3) + dx;
        float y0f = floorf(py), x0f = floorf(pxf);
        float wy1 = py - y0f, wx1 = pxf - x0f;
        float wy0 = 1.f - wy1, wx0 = 1.f - wx1;
        int y0 = (int)y0f, x0 = (int)x0f;
        float my0 = ((unsigned)y0 < 128u) ? m : 0.f;
        float my1 = ((unsigned)(y0 + 1) < 128u) ? m : 0.f;
        float vx0 = ((unsigned)x0 < 128u) ? 1.f : 0.f;
        float vx1 = ((unsigned)(x0 + 1) < 128u) ? 1.f : 0.f;
        w00[i] = wy0 * wx0 * my0 * vx0;
        w01[i] = wy0 * wx1 * my0 * vx1;
        w10[i] = wy1 * wx0 * my1 * vx0;
        w11[i] = wy1 * wx1 * my1 * vx1;
        int y0c = min(max(y0, 0), 127) * (WW * 64);
        int y1c = min(max(y0 + 1, 0), 127) * (WW * 64);
        int x0c = min(max(x0, 0), 127) * 64 + cl * 8;
        int x1c = min(max(x0 + 1, 0), 127) * 64 + cl * 8;
        o00[i] = y0c + x0c; o01[i] = y0c + x1c;
        o10[i] = y1c + x0c; o11[i] = y1c + x1c;
    }
#pragma unroll
    for (int kf = KF0; kf < KF1; ++kf) {
        const int i = kf - KF0;
        short8 v00 = *(const short8*)(xTb + o00[i]);
        short8 v01 = *(const short8*)(xTb + o01[i]);
        short8 v10 = *(const short8*)(xTb + o10[i]);
        short8 v11 = *(const short8*)(xTb + o11[i]);
        short8 res;
#pragma unroll
        for (int j = 0; j < 8; ++j) {
            float f = w00[i] * bf2f_s(v00[j]) + w01[i] * bf2f_s(v01[j])
                    + w10[i] * bf2f_s(v10[j]) + w11[i] * bf2f_s(v11[j]);
            res[j] = (short)f2bf(f);
        }
        int baddr = ((px * KLOC + (kf - KF0) * 64 + cl * 8) * 2) ^ ((px & 7) << 4);
        *(short8*)(s_val + baddr) = res;
    }
}

template<int NK>
__device__ __forceinline__ void mfma_half(
        const unsigned short* __restrict__ wrow0,
        const unsigned short* __restrict__ wrow1,
        const char* __restrict__ s_val,
        int vbase, int vswz, int g4,
        f32x4& acc0, f32x4& acc1) {
#pragma unroll
    for (int kk = 0; kk < NK; ++kk) {
        int k0 = kk * 32 + g4 * 8;
        short8 bfrag = *(const short8*)(s_val + ((vbase + k0 * 2) ^ vswz));
        short8 a0 = *(const short8*)(wrow0 + k0);
        short8 a1 = *(const short8*)(wrow1 + k0);
        acc0 = __builtin_amdgcn_mfma_f32_16x16x32_bf16(a0, bfrag, acc0, 0, 0, 0);
        acc1 = __builtin_amdgcn_mfma_f32_16x16x32_bf16(a1, bfrag, acc1, 0, 0, 0);
    }
}

// ---------------- Kernel 3: fused conv-MFMA + gather + split-K MFMA ----------------
__global__ void __launch_bounds__(256, 4) fused_dcn_kernel(
        const unsigned short* __restrict__ xT,
        const unsigned short* __restrict__ wtoff,
        const float* __restrict__ b_off,
        const unsigned short* __restrict__ wt,
        float* __restrict__ out) {
    __shared__ float s_om[PIX * 28];            // 3584 B (stride 28, 27 used)
    __shared__ char  s_val[PIX * KLOC * 2];     // 20480 B, swizzled [px][k'] bf16

    int t = threadIdx.x;
    int blk0 = blockIdx.x;
    int blk = (blk0 & 7) * 512 + (blk0 >> 3);   // XCD swizzle (4096 = 8*512, bijective)
    int b = blk >> 9;
    int rem = blk & 511;
    int h = rem >> 2;                            // tile = 32 px of one row
    int w0 = (rem & 3) << 5;

    int lane = t & 63;
    int wv = t >> 6;
    int l15 = lane & 15;
    int g4 = lane >> 4;

    const unsigned short* xTb = xT + (size_t)b * HW * 64;

    // ---- phase A: offset conv (27ch) via MFMA, im2col direct from xT ----
    {
        int Nt = wv & 1, Mt = wv >> 1;
        int px = Nt * 16 + l15;
        int colbase = w0 + px - 1;
        f32x4 acc = {0.f, 0.f, 0.f, 0.f};
        const unsigned short* arow = wtoff + (size_t)(Mt * 16 + l15) * KDIM;
#pragma unroll
        for (int kk = 0; kk < 18; ++kk) {
            int kf = kk >> 1;
            int ky = kf / 3, kx = kf % 3;
            int cb = (kk & 1) * 32 + g4 * 8;
            int row = h - 1 + ky;
            int col = colbase + kx;
            short8 bfrag = {0, 0, 0, 0, 0, 0, 0, 0};
            if ((unsigned)row < 128u && (unsigned)col < 128u)
                bfrag = *(const short8*)(xTb + ((size_t)row * 128 + (size_t)col) * 64 + cb);
            short8 afrag = *(const short8*)(arow + kk * 32 + g4 * 8);
            acc = __builtin_amdgcn_mfma_f32_16x16x32_bf16(afrag, bfrag, acc, 0, 0, 0);
        }
        int ob = Mt * 16 + g4 * 4;
#pragma unroll
        for (int r = 0; r < 4; ++r) {
            if (ob + r < 27)
                s_om[px * 28 + ob + r] = acc[r] + b_off[ob + r];
        }
    }
    __syncthreads();

    // ---- main GEMM state (per wave: 16px x 32out) ----
    int px_base = (wv & 1) * 16;
    int out_base = (wv >> 1) * 32;
    f32x4 acc0 = {0.f, 0.f, 0.f, 0.f};
    f32x4 acc1 = {0.f, 0.f, 0.f, 0.f};
    const unsigned short* wrow0 = wt + (size_t)(out_base + l15) * KDIM;
    const unsigned short* wrow1 = wrow0 + 16 * KDIM;
    int vrow = px_base + l15;
    int vbase = vrow * KLOC * 2;
    int vswz = (vrow & 7) << 4;

    // ---- half 0: kf 0..3 (K' = 256) ----
    gather_half<0, 4>(xTb, s_om, s_val, t, h, w0);
    __syncthreads();
    mfma_half<8>(wrow0, wrow1, s_val, vbase, vswz, g4, acc0, acc1);
    __syncthreads();

    // ---- half 1: kf 4..8 (K' = 320) ----
    gather_half<4, 9>(xTb, s_om, s_val, t, h, w0);
    __syncthreads();
    mfma_half<10>(wrow0 + 256, wrow1 + 256, s_val, vbase, vswz, g4, acc0, acc1);

    // ---- store ----
    float* obp = out + (size_t)b * COUT * HW + (size_t)h * WW + w0 + px_base + l15;
    int orow0 = out_base + g4 * 4;
#pragma unroll
    for (int r = 0; r < 4; ++r) {
        obp[(size_t)(orow0 + r) * HW]      = acc0[r];
        obp[(size_t)(orow0 + 16 + r) * HW] = acc1[r];
    }
}

extern "C" void kernel_launch(void* const* d_in, const int* in_sizes, int n_in,
                              void* d_out, int out_size, void* d_ws, size_t ws_size,
                              hipStream_t stream) {
    (void)in_sizes; (void)n_in; (void)out_size; (void)ws_size;
    const float* x        = (const float*)d_in[0];
    const float* w_offset = (const float*)d_in[1];
    const float* b_offset = (const float*)d_in[2];
    const float* w_dcn    = (const float*)d_in[3];
    float* out = (float*)d_out;

    unsigned short* xT    = (unsigned short*)d_ws;                      // 16,777,216 B
    unsigned short* wt    = (unsigned short*)((char*)d_ws + 16777216);  // 73,728 B
    unsigned short* wtoff = (unsigned short*)((char*)d_ws + 16850944);  // 36,864 B

    xpose_kernel<<<4096, 256, 0, stream>>>(x, xT);
    wcast_kernel<<<216, 256, 0, stream>>>(w_dcn, w_offset, wt, wtoff);
    fused_dcn_kernel<<<4096, 256, 0, stream>>>(xT, wtoff, b_offset, wt, out);
}